// Round 1
// baseline (682.958 us; speedup 1.0000x reference)
//
#include <hip/hip_runtime.h>
#include <hip/hip_fp16.h>

#define N_NODES 50000
#define N_EDGES 600000

typedef _Float16 f16x8 __attribute__((ext_vector_type(8)));
typedef _Float16 f16x4 __attribute__((ext_vector_type(4)));
typedef float f32x4 __attribute__((ext_vector_type(4)));

// ws layout (offsets in halfs):
//   w1ab : [512][128]  (n<256: W1[n][k] ; n>=256: W1[n-256][128+k])
//   w1c  : [256][128]  (W1[n][256+k])
//   w2h  : [128][256]  (W2[n][k])
//   xab  : [50048][512] (node precompute: x[v] @ [W1a;W1b]^T, fp16)
#define W1AB_OFF 0
#define W1C_OFF  65536
#define W2_OFF   98304
#define XAB_OFF  131072
// total halfs = 131072 + 50048*512 = 25755648  (~51.5 MB)

// ---------------------------------------------------------------------------
// P0: convert weights fp32 -> fp16, repacked
__global__ __launch_bounds__(256) void convert_weights(
    const float* __restrict__ W1, const float* __restrict__ W2,
    _Float16* __restrict__ ws16) {
  int i = blockIdx.x * 256 + threadIdx.x;  // 0 .. 131071
  if (i < 65536) {                         // w1ab
    int n = i >> 7, k = i & 127;
    float v = (n < 256) ? W1[n * 384 + k] : W1[(n - 256) * 384 + 128 + k];
    ws16[W1AB_OFF + i] = (_Float16)v;
  } else if (i < 98304) {                  // w1c
    int j = i - 65536;
    int n = j >> 7, k = j & 127;
    ws16[W1C_OFF + j] = (_Float16)W1[n * 384 + 256 + k];
  } else {                                 // w2
    int j = i - 98304;
    ws16[W2_OFF + j] = (_Float16)W2[j];
  }
}

// ---------------------------------------------------------------------------
// P1: per-node precompute  xab[v][n] = sum_k x16[v][k] * w1ab[n][k]
__global__ __launch_bounds__(256, 2) void node_precompute(
    const float* __restrict__ x, _Float16* __restrict__ ws16) {
  const _Float16* __restrict__ w1ab = ws16 + W1AB_OFF;
  _Float16* __restrict__ xab = ws16 + XAB_OFF;

  __shared__ __align__(16) _Float16 xt[64][136];  // +8 halfs pad
  int tid = threadIdx.x;
  int v0 = blockIdx.x * 64;

  // stage x tile (fp32 -> fp16), rows clamped for last partial block
#pragma unroll
  for (int it = 0; it < 8; ++it) {
    int f = tid + it * 256;          // float4 id, 2048 total
    int r = f >> 5;                  // 32 float4 per row
    int c = (f & 31) * 4;
    int vr = v0 + r;
    if (vr > N_NODES - 1) vr = N_NODES - 1;
    float4 val = *(const float4*)&x[(size_t)vr * 128 + c];
    f16x4 h;
    h[0] = (_Float16)val.x; h[1] = (_Float16)val.y;
    h[2] = (_Float16)val.z; h[3] = (_Float16)val.w;
    *(f16x4*)&xt[r][c] = h;
  }
  __syncthreads();

  int lane = tid & 63;
  int w = tid >> 6;                  // wave id 0..3, owns n in [w*128, w*128+128)
  int m16 = lane & 15;
  int quad = lane >> 4;

  for (int nn = 0; nn < 2; ++nn) {
    f32x4 acc[4][4] = {};
#pragma unroll
    for (int kk = 0; kk < 4; ++kk) {
      f16x8 a[4];
#pragma unroll
      for (int m = 0; m < 4; ++m)
        a[m] = *(const f16x8*)&xt[m * 16 + m16][kk * 32 + quad * 8];
#pragma unroll
      for (int j = 0; j < 4; ++j) {
        int n = w * 128 + nn * 64 + j * 16 + m16;
        f16x8 b = *(const f16x8*)&w1ab[n * 128 + kk * 32 + quad * 8];
#pragma unroll
        for (int m = 0; m < 4; ++m)
          acc[m][j] = __builtin_amdgcn_mfma_f32_16x16x32_f16(a[m], b, acc[m][j], 0, 0, 0);
      }
    }
#pragma unroll
    for (int m = 0; m < 4; ++m)
#pragma unroll
      for (int j = 0; j < 4; ++j)
#pragma unroll
        for (int r = 0; r < 4; ++r) {
          int v = v0 + m * 16 + quad * 4 + r;
          if (v < N_NODES) {
            int n = w * 128 + nn * 64 + j * 16 + m16;
            xab[(size_t)v * 512 + n] = (_Float16)acc[m][j][r];
          }
        }
  }
}

// ---------------------------------------------------------------------------
// Main fused kernel: 64 edges per block, 4 waves (256 threads).
//   phase1: h_pre = ea16 @ w1c^T  (M=64,N=256,K=128)
//   epi1  : h = relu(h_pre + xa[row] + xb[col] + b1) -> LDS fp16
//   phase2: out = h @ w2^T + b2   (M=64,N=128,K=256) -> fp32 global
__global__ __launch_bounds__(256, 3) void edge_mlp(
    const int* __restrict__ ei, const float* __restrict__ ea,
    const float* __restrict__ b1, const float* __restrict__ b2,
    const _Float16* __restrict__ ws16, float* __restrict__ out) {
  const _Float16* __restrict__ w1c = ws16 + W1C_OFF;
  const _Float16* __restrict__ w2h = ws16 + W2_OFF;
  const _Float16* __restrict__ xab = ws16 + XAB_OFF;

  __shared__ __align__(16) _Float16 eat[64][136];  // ea tile, +8 pad
  __shared__ __align__(16) _Float16 sh[64][264];   // s then h (aliased), +8 pad
  __shared__ int eidx[128];                        // [0..63]=row, [64..127]=col

  int tid = threadIdx.x;
  int e0 = blockIdx.x * 64;

  if (tid < 128) {
    int which = tid >> 6;  // 0 row, 1 col
    int el = tid & 63;
    int v = ei[(size_t)which * N_EDGES + e0 + el];
    if (v < 0) v = 0;
    if (v > N_NODES - 1) v = N_NODES - 1;
    eidx[tid] = v;
  }
  __syncthreads();

  int lane = tid & 63;
  int w = tid >> 6;

  // stage ea tile (fp32 -> fp16)
#pragma unroll
  for (int it = 0; it < 8; ++it) {
    int f = tid + it * 256;
    int r = f >> 5;
    int c = (f & 31) * 4;
    float4 val = *(const float4*)&ea[(size_t)(e0 + r) * 128 + c];
    f16x4 h;
    h[0] = (_Float16)val.x; h[1] = (_Float16)val.y;
    h[2] = (_Float16)val.z; h[3] = (_Float16)val.w;
    *(f16x4*)&eat[r][c] = h;
  }

  // stage s = xa[row] + xb[col] + b1  (each wave: 16 edges; lane covers 4 cols)
  {
    float4 bb = *(const float4*)&b1[lane * 4];
#pragma unroll 4
    for (int i = 0; i < 16; ++i) {
      int el = w * 16 + i;
      int vr = eidx[el];
      int vc = eidx[64 + el];
      f16x4 va = *(const f16x4*)&xab[(size_t)vr * 512 + lane * 4];
      f16x4 vb = *(const f16x4*)&xab[(size_t)vc * 512 + 256 + lane * 4];
      f16x4 s;
      s[0] = (_Float16)((float)va[0] + (float)vb[0] + bb.x);
      s[1] = (_Float16)((float)va[1] + (float)vb[1] + bb.y);
      s[2] = (_Float16)((float)va[2] + (float)vb[2] + bb.z);
      s[3] = (_Float16)((float)va[3] + (float)vb[3] + bb.w);
      *(f16x4*)&sh[el][lane * 4] = s;
    }
  }
  __syncthreads();

  int m16 = lane & 15;
  int quad = lane >> 4;

  // phase 1: wave w owns n in [w*64, w*64+64)
  f32x4 acc[4][4] = {};
#pragma unroll
  for (int kk = 0; kk < 4; ++kk) {
    f16x8 a[4];
#pragma unroll
    for (int m = 0; m < 4; ++m)
      a[m] = *(const f16x8*)&eat[m * 16 + m16][kk * 32 + quad * 8];
#pragma unroll
    for (int j = 0; j < 4; ++j) {
      int n = w * 64 + j * 16 + m16;
      f16x8 b = *(const f16x8*)&w1c[n * 128 + kk * 32 + quad * 8];
#pragma unroll
      for (int m = 0; m < 4; ++m)
        acc[m][j] = __builtin_amdgcn_mfma_f32_16x16x32_f16(a[m], b, acc[m][j], 0, 0, 0);
    }
  }

  // epilogue 1: h = relu(acc + s); write back into sh (same lane owns same slot)
#pragma unroll
  for (int m = 0; m < 4; ++m)
#pragma unroll
    for (int j = 0; j < 4; ++j) {
      int c = w * 64 + j * 16 + m16;
#pragma unroll
      for (int r = 0; r < 4; ++r) {
        int row = m * 16 + quad * 4 + r;
        float v = acc[m][j][r] + (float)sh[row][c];
        v = v > 0.f ? v : 0.f;
        sh[row][c] = (_Float16)v;
      }
    }
  __syncthreads();

  // phase 2: wave w owns n in [w*32, w*32+32)
  f32x4 acc2[4][2] = {};
#pragma unroll
  for (int kk = 0; kk < 8; ++kk) {
    f16x8 a[4];
#pragma unroll
    for (int m = 0; m < 4; ++m)
      a[m] = *(const f16x8*)&sh[m * 16 + m16][kk * 32 + quad * 8];
#pragma unroll
    for (int j = 0; j < 2; ++j) {
      int n = w * 32 + j * 16 + m16;
      f16x8 b = *(const f16x8*)&w2h[n * 256 + kk * 32 + quad * 8];
#pragma unroll
      for (int m = 0; m < 4; ++m)
        acc2[m][j] = __builtin_amdgcn_mfma_f32_16x16x32_f16(a[m], b, acc2[m][j], 0, 0, 0);
    }
  }

  // epilogue 2: out = acc2 + b2  (fp32)
#pragma unroll
  for (int m = 0; m < 4; ++m)
#pragma unroll
    for (int j = 0; j < 2; ++j) {
      int n = w * 32 + j * 16 + m16;
      float bias = b2[n];
#pragma unroll
      for (int r = 0; r < 4; ++r) {
        int e = e0 + m * 16 + quad * 4 + r;
        out[(size_t)e * 128 + n] = acc2[m][j][r] + bias;
      }
    }
}

// ---------------------------------------------------------------------------
extern "C" void kernel_launch(void* const* d_in, const int* in_sizes, int n_in,
                              void* d_out, int out_size, void* d_ws, size_t ws_size,
                              hipStream_t stream) {
  const float* x  = (const float*)d_in[0];
  const int*   ei = (const int*)d_in[1];
  const float* ea = (const float*)d_in[2];
  const float* W1 = (const float*)d_in[3];
  const float* b1 = (const float*)d_in[4];
  const float* W2 = (const float*)d_in[5];
  const float* b2 = (const float*)d_in[6];
  float* out = (float*)d_out;
  _Float16* ws16 = (_Float16*)d_ws;

  convert_weights<<<512, 256, 0, stream>>>(W1, W2, ws16);
  node_precompute<<<(N_NODES + 63) / 64, 256, 0, stream>>>(x, ws16);
  edge_mlp<<<N_EDGES / 64, 256, 0, stream>>>(ei, ea, b1, b2, ws16, out);
}